// Round 1
// 196.658 us; speedup vs baseline: 1.1104x; 1.1104x over previous
//
#include <hip/hip_runtime.h>
#include <hip/hip_bf16.h>

#define B_ 4096
#define D_ 32
#define H_ 1024
#define CS 512                 // activation chunk stride: [chunk][16 rows][32] shorts
#define WPK_L 1079296          // shorts per hidden-layer weight pack (= 2048*sum(idx+1))

typedef __attribute__((ext_vector_type(8))) short short8;
typedef __attribute__((ext_vector_type(4))) float floatx4;

// non-draining workgroup barrier: LDS visibility only, leaves global loads in flight
#define BAR() __asm__ __volatile__("s_waitcnt lgkmcnt(0)\n\ts_barrier" ::: "memory")

__device__ inline unsigned short f2bf(float f) {      // fp32 -> bf16 bits, RNE
    unsigned u = __float_as_uint(f);
    unsigned r = (u + 0x7FFF + ((u >> 16) & 1)) >> 16;
    return (unsigned short)r;
}

// degree-sorted order: degree 0 -> slots [0,34), degree d>=1 -> slots [33d+1, 33d+34)
__device__ inline int degs(int hp) { return (hp < 34) ? 0 : (hp - 1) / 33; }
__device__ inline int permf(int hp) {                  // sorted slot -> original h
    int d = degs(hp);
    int r = d ? (hp - 33 * d - 1) : hp;
    return d + 31 * r;
}
__device__ inline int band0i(int idx) {                // fresh-band base slot at step idx>=1
    int nb0 = (idx == 1) ? 0 : 33 * idx - 32;
    return (nb0 > H_ - 64) ? H_ - 64 : nb0;
}

// ---- single fused prep: per-step band packs (direct scatter), W0 packs, Wout packs, biases ----
__global__ __launch_bounds__(256) void prep_all(
        const float* __restrict__ Wh, const float* __restrict__ W0,
        const float* __restrict__ Wout, const float* __restrict__ b0,
        const float* __restrict__ bh,
        unsigned short* __restrict__ Wpk, unsigned short* __restrict__ W0pk,
        unsigned short* __restrict__ Wopk, float* __restrict__ b0p,
        float* __restrict__ bhp) {
    __shared__ float row[H_];
    __shared__ unsigned short rb[H_];
    int b = blockIdx.x, t = threadIdx.x;
    if (b < 2048) {                          // Wh row (l, np) -> direct scatter into band packs
        int l = b >> 10, np = b & 1023;
        const float* src = Wh + ((size_t)l << 20) + ((size_t)permf(np) << 10);
        ((float4*)row)[t] = ((const float4*)src)[t];
        __syncthreads();
        int dn = degs(np);
        unsigned short o[4];
        #pragma unroll
        for (int j = 0; j < 4; j++) {
            int kp = t * 4 + j;
            o[j] = (dn >= degs(kp)) ? f2bf(row[permf(kp)]) : (unsigned short)0;
        }
        ((ushort4*)rb)[t] = ushort4{o[0], o[1], o[2], o[3]};
        __syncthreads();
        // row np lives in band windows [nb0, nb0+64) for ~2 idx values; write its segments
        for (int idx = 1; idx < 32; idx++) {
            int nb0 = band0i(idx);
            int j = np - nb0;
            if (j < 0 || j >= 64) continue;              // uniform per block
            int nq = (idx + 1) * 4;                      // 16B quads: nk chunks x 64B
            if (t < nq) {
                int c = t >> 2, qd = t & 3;
                size_t base = (size_t)l * WPK_L + (size_t)1024 * (idx - 1) * (idx + 2);
                *(uint4*)(Wpk + base + c * 2048 + j * 32 + qd * 8) =
                    *(const uint4*)(rb + c * 32 + qd * 8);
            }
        }
    } else if (b < 2079) {                   // W0 band packs [idx][slot64][32]
        int idx = b - 2047;
        int nb0 = band0i(idx);
        int j = t >> 2, ko = (t & 3) * 8;
        int n = nb0 + j;
        int dn = degs(n);
        const float* srow = W0 + (size_t)permf(n) * 32;
        union { unsigned short o[8]; uint4 v; } u;
        #pragma unroll
        for (int e = 0; e < 8; e++)
            u.o[e] = (dn >= ko + e) ? f2bf(srow[ko + e]) : (unsigned short)0;
        *(uint4*)(W0pk + (idx - 1) * 2048 + j * 32 + ko) = u.v;
    } else if (b < 3103) {                   // Wout bf16 packs [idx][c][col16][32], full prefix
        int bb = b - 2079;
        int idx = bb >> 5, c = bb & 31;
        int ns = idx ? 33 * idx + 1 : 0;     // live-prefix length at step idx
        #pragma unroll
        for (int uu = 0; uu < 2; uu++) {
            int e = t + uu * 256;
            int col = e >> 5, k = e & 31;
            int h = c * 32 + k;
            unsigned short v = 0;
            if (col < 2 && h < ns)
                v = f2bf(Wout[(size_t)(idx + col * 32) * H_ + permf(h)]);
            Wopk[(size_t)bb * 512 + e] = v;
        }
    } else {                                 // biases
        int tt = (b - 3103) * 256 + t;       // over 3*1024
        int hp = tt & 1023;
        int p = permf(hp);
        if (tt < 1024) b0p[hp] = b0[p];
        else if (tt < 2048) bhp[hp] = bh[p];
        else bhp[1024 + hp] = bh[1024 + p];
    }
}

__device__ inline floatx4 mfma16(short8 a, short8 b, floatx4 c) {
    return __builtin_amdgcn_mfma_f32_16x16x32_bf16(a, b, c, 0, 0, 0);
}

// ---- band K-partial against register-resident weights (rb[8], statically indexed) ----
#define BAND_PARTIAL(act, outv) do {                                          \
    const unsigned short* ap_ = (act) + arow;                                 \
    floatx4 x_ = {0.f, 0.f, 0.f, 0.f}, y_ = {0.f, 0.f, 0.f, 0.f};             \
    _Pragma("unroll")                                                         \
    for (int j_ = 0; j_ < 8; j_++) {                                          \
        if (j_ < nch) {                                                       \
            short8 a_ = *(const short8*)(ap_ + (size_t)(c0 + j_) * CS);       \
            if (j_ & 1) y_ = mfma16(a_, rb[j_], y_);                          \
            else        x_ = mfma16(a_, rb[j_], x_);                          \
        }                                                                     \
    }                                                                         \
    outv = x_ + y_;                                                           \
} while (0)

// ---- mega-kernel: 256 wgs x 16 rows x 16 waves; 32-step chain in LDS ----
// Weights are register-prefetched one phase ahead: L3 weights loaded right after
// L2's MFMAs, next-step L2 weights right after L3's MFMAs, Wout/W0/bias a full
// step ahead. BAR() leaves vmcnt alone so the loads fly across barriers.
__global__ __launch_bounds__(1024) void mega_kernel(
        const float* __restrict__ z,
        const unsigned short* __restrict__ W0pk,
        const float* __restrict__ b0p,
        const unsigned short* __restrict__ Wpk,
        const float* __restrict__ bhp,
        const unsigned short* __restrict__ Wopk,
        const float* __restrict__ bout,
        float* __restrict__ xout) {
    __shared__ unsigned short aS[3 * 32 * CS];     // a1,a2,a3: [c][16 rows][32], 32KB each
    __shared__ unsigned short xbS[16 * 32];        // running x, bf16
    __shared__ float xsS[512];                     // running x, fp32 [row][col]
    __shared__ float zsT[512];                     // z transposed [col][row] (conflict-free read)
    __shared__ floatx4 redS[12 * 64];              // K-split partials [q-1][s][lane]
    __shared__ float redO[16 * 32];                // out-dot partials [wave][col*16+m]

    const int tid = threadIdx.x;
    const int wave = tid >> 6, lane = tid & 63;
    const int frow = lane & 15, fk = lane >> 4;
    const int arow = frow * 32 + fk * 8;
    const int s = wave & 3, q = wave >> 2;
    const int m0 = blockIdx.x * 16;

    {   // zero-init (garbage x 0-weight must stay 0; matches x0 = 0)
        uint4 zz = {0u, 0u, 0u, 0u};
        for (int i = tid; i < 3 * 32 * CS / 8; i += 1024) ((uint4*)aS)[i] = zz;
        if (tid < 64)  ((uint4*)xbS)[tid] = zz;
        if (tid < 128) ((uint4*)xsS)[tid] = zz;
        if (tid < 128) ((uint4*)redO)[tid] = zz;
        if (tid < 128) {
            float4 v = ((const float4*)(z + (size_t)m0 * 32))[tid];
            int row = tid >> 3, c4 = (tid & 7) * 4;
            zsT[(c4 + 0) * 16 + row] = v.x;
            zsT[(c4 + 1) * 16 + row] = v.y;
            zsT[(c4 + 2) * 16 + row] = v.z;
            zsT[(c4 + 3) * 16 + row] = v.w;
        }
    }
    __syncthreads();

    unsigned short* a1 = aS;
    unsigned short* a2 = aS + 32 * CS;
    unsigned short* a3 = aS + 64 * CS;

    // ---- register-resident weight state ----
    short8 rb[8];                 // current band weights (layer2, then layer3, alternating)
    short8 rbf;                   // W0 fragment for layer1 (q==0 only)
    short8 rwo0, rwo1;            // Wout fragments for out-dot
    float pb0 = 0.f, pb2 = 0.f, pb3 = 0.f;     // biases (q==0 only)
    float pbo_m = 0.f, pbo_s = 0.f;            // bout (wave 0 only)

    rwo0 = *(const short8*)(Wopk + (size_t)((wave * 2) * 16 + frow) * 32 + fk * 8);
    rwo1 = *(const short8*)(Wopk + (size_t)((wave * 2 + 1) * 16 + frow) * 32 + fk * 8);
    if (wave == 0) { pbo_m = bout[0]; pbo_s = bout[D_]; }

    auto pfL2 = [&](int nidx) {   // layer-2 band weights + layer1/bias state for step nidx
        const int nkn = nidx + 1;
        const int nk4n = (nkn + 3) >> 2;
        const int c0n = q * nk4n;
        const int c1n = (c0n + nk4n < nkn) ? c0n + nk4n : nkn;
        const int nchn = c1n - c0n;
        const unsigned short* w2 = Wpk + (size_t)1024 * (nidx - 1) * (nidx + 2)
                                 + s * 512 + frow * 32 + fk * 8;
        #pragma unroll
        for (int j = 0; j < 8; j++)
            if (j < nchn) rb[j] = *(const short8*)(w2 + (size_t)(c0n + j) * 2048);
        if (q == 0) {
            const int nb0n = band0i(nidx);
            const int slotn = nb0n + s * 16 + frow;
            rbf = *(const short8*)(W0pk + (nidx - 1) * 2048 + (s * 16 + frow) * 32 + fk * 8);
            pb0 = b0p[slotn];
            pb2 = bhp[slotn];
            pb3 = bhp[H_ + slotn];
        }
    };
    auto pfL3 = [&](int cidx) {   // layer-3 band weights for current step cidx
        const int nkn = cidx + 1;
        const int nk4n = (nkn + 3) >> 2;
        const int c0n = q * nk4n;
        const int c1n = (c0n + nk4n < nkn) ? c0n + nk4n : nkn;
        const int nchn = c1n - c0n;
        const unsigned short* w3 = Wpk + WPK_L + (size_t)1024 * (cidx - 1) * (cidx + 2)
                                 + s * 512 + frow * 32 + fk * 8;
        #pragma unroll
        for (int j = 0; j < 8; j++)
            if (j < nchn) rb[j] = *(const short8*)(w3 + (size_t)(c0n + j) * 2048);
    };

    for (int idx = 0; idx < 32; idx++) {
        if (idx > 0) {
            const int nb0 = band0i(idx);
            const int slot = nb0 + s * 16 + frow;
            const int nk = idx + 1;
            const int nk4 = (nk + 3) >> 2;
            const int c0 = q * nk4;
            const int c1m = (c0 + nk4 < nk) ? c0 + nk4 : nk;
            const int nch = c1m - c0;
            const int wsl = (slot >> 5) * CS + (slot & 31);
            const float pb3c = pb3;            // pb3 is overwritten by pfL2(idx+1) below

            // ---- layer 1 band (q==0): K=32 single chunk, weights pre-loaded in rbf ----
            if (q == 0) {
                short8 a = *(const short8*)(xbS + arow);
                floatx4 acc = {0.f, 0.f, 0.f, 0.f};
                acc = mfma16(a, rbf, acc);
                #pragma unroll
                for (int r = 0; r < 4; r++)
                    a1[wsl + (fk * 4 + r) * 32] = f2bf(fmaxf(acc[r] + pb0, 0.f));
            }
            BAR();                                         // A: a1 visible

            // ---- layer 2 band ----
            {
                floatx4 p;
                BAND_PARTIAL(a1, p);
                pfL3(idx);                                 // issue L3 weight loads (in flight across B/C)
                if (q) redS[((q - 1) * 4 + s) * 64 + lane] = p;
                BAR();                                     // B: partials visible
                if (q == 0) {
                    p = p + redS[s * 64 + lane] + redS[(4 + s) * 64 + lane]
                          + redS[(8 + s) * 64 + lane];
                    #pragma unroll
                    for (int r = 0; r < 4; r++)
                        a2[wsl + (fk * 4 + r) * 32] = f2bf(fmaxf(p[r] + pb2, 0.f));
                }
                BAR();                                     // C: a2 visible
            }

            // ---- layer 3 band ----
            {
                floatx4 g;
                BAND_PARTIAL(a2, g);
                if (idx < 31) pfL2(idx + 1);               // issue next-step L2 weight loads
                if (q) redS[((q - 1) * 4 + s) * 64 + lane] = g;
                BAR();                                     // D: partials visible
                if (q == 0) {
                    g = g + redS[s * 64 + lane] + redS[(4 + s) * 64 + lane]
                          + redS[(8 + s) * 64 + lane];
                    #pragma unroll
                    for (int r = 0; r < 4; r++)
                        a3[wsl + (fk * 4 + r) * 32] = f2bf(fmaxf(g[r] + pb3c, 0.f));
                }
                BAR();                                     // E: a3 visible
            }
        } else {
            pfL2(1);                                       // first band prefetch, lands during idx=0
        }

        const float bm = pbo_m, bs = pbo_s;                // current-step bout (wave 0)

        // ---- out-dot: wave w covers a3 chunks {2w, 2w+1}; weights pre-loaded in rwo* ----
        {
            floatx4 oacc = {0.f, 0.f, 0.f, 0.f};
            short8 av0 = *(const short8*)(a3 + (wave * 2) * CS + arow);
            short8 av1 = *(const short8*)(a3 + (wave * 2 + 1) * CS + arow);
            oacc = mfma16(av0, rwo0, oacc);
            oacc = mfma16(av1, rwo1, oacc);
            if (idx < 31) {                                // reload for next step (dead after MFMAs)
                rwo0 = *(const short8*)(Wopk + (size_t)(((idx + 1) * 32 + wave * 2) * 16 + frow) * 32 + fk * 8);
                rwo1 = *(const short8*)(Wopk + (size_t)(((idx + 1) * 32 + wave * 2 + 1) * 16 + frow) * 32 + fk * 8);
                if (wave == 0) { pbo_m = bout[idx + 1]; pbo_s = bout[idx + 1 + D_]; }
            }
            if (frow < 2) {
                #pragma unroll
                for (int r = 0; r < 4; r++)
                    redO[wave * 32 + frow * 16 + fk * 4 + r] = oacc[r];
            }
        }
        BAR();                                             // F: redO visible

        // ---- final reduce: 64 lanes of wave 0 (8 loads deep), shfl to combine ----
        if (wave == 0) {
            const int col = lane & 31;
            const int wbase = (lane >> 5) * 8;
            float v = 0.f;
            #pragma unroll
            for (int w = 0; w < 8; w++) v += redO[(wbase + w) * 32 + col];
            v += __shfl_xor(v, 32);                        // all lanes: total for col=lane&31
            float vs = __shfl(v, (lane & 15) + 16);        // log_std column for this row
            if (lane < 16) {
                float xi = fmaf(zsT[idx * 16 + lane], expf(bs + vs), bm + v);
                xsS[lane * 32 + idx] = xi;
                xbS[lane * 32 + idx] = f2bf(xi);
            }
        }
        BAR();                                             // G: x visible
    }

    __syncthreads();
    if (tid < 128)
        ((float4*)(xout + (size_t)m0 * 32))[tid] = ((const float4*)xsS)[tid];
}

extern "C" void kernel_launch(void* const* d_in, const int* in_sizes, int n_in,
                              void* d_out, int out_size, void* d_ws, size_t ws_size,
                              hipStream_t stream) {
    const float* z    = (const float*)d_in[0];
    const float* W0   = (const float*)d_in[1];
    const float* b0   = (const float*)d_in[2];
    const float* Wh   = (const float*)d_in[3];   // [2, H, H]
    const float* bh   = (const float*)d_in[4];   // [2, H]
    const float* Wout = (const float*)d_in[5];   // [64, H]
    const float* bout = (const float*)d_in[6];   // [64]

    float* x = (float*)d_out;                          // [B, D] output
    unsigned short* Wpk  = (unsigned short*)d_ws;      // 2 * WPK_L band packs
    unsigned short* W0pk = Wpk + 2 * WPK_L;            // 31 * 2048
    unsigned short* Wopk = W0pk + 31 * 2048;           // 32 * 32 * 512
    float* b0p = (float*)(Wopk + 32 * 32 * 512);       // [H]
    float* bhp = b0p + H_;                             // [2, H]

    prep_all<<<3115, 256, 0, stream>>>(Wh, W0, Wout, b0, bh, Wpk, W0pk, Wopk, b0p, bhp);

    mega_kernel<<<B_ / 16, 1024, 0, stream>>>(z, W0pk, b0p, Wpk, bhp, Wopk, bout, x);
}